// Round 1
// baseline (286.164 us; speedup 1.0000x reference)
//
#include <hip/hip_runtime.h>

#define B_    4
#define C_    256
#define H_    64
#define W_    64
#define HW_   4096
#define NG_   32
#define CPG_  8
#define KK_   9
#define NOFF_ 18

typedef __attribute__((ext_vector_type(8))) short short8;
typedef __attribute__((ext_vector_type(4))) short short4v;
typedef __attribute__((ext_vector_type(4))) float floatx4;
typedef __attribute__((ext_vector_type(16))) float floatx16;

static __device__ __forceinline__ short f2bf(float f) {
    union { float f; unsigned u; } v; v.f = f;
    unsigned r = v.u + 0x7fff + ((v.u >> 16) & 1);   // RNE
    return (short)(r >> 16);
}
static __device__ __forceinline__ float bf2f(short s) {
    union { unsigned u; float f; } v;
    v.u = ((unsigned)(unsigned short)s) << 16;
    return v.f;
}
// packed f32x2 -> bf16x2 (RNE), single VALU op
static __device__ __forceinline__ unsigned pkbf(float lo, float hi) {
    unsigned r;
    asm("v_cvt_pk_bf16_f32 %0, %1, %2" : "=v"(r) : "v"(lo), "v"(hi));
    return r;
}

// ---------------------------------------------------------------------------
// K1: GroupNorm (32 groups) + ReLU -> bf16 [C][HW]. fp32-input variant.
// One block (1024 thr) per (b, group). (Also used on the fp32 y1 accumulator.)
// ---------------------------------------------------------------------------
__global__ __launch_bounds__(1024) void gn_relu_f32_kernel(
    const float* __restrict__ in, const float* __restrict__ gamma,
    const float* __restrict__ beta, short* __restrict__ outb)
{
    int b = blockIdx.x >> 5;
    int g = blockIdx.x & 31;
    const int N = CPG_ * HW_;              // 32768
    size_t base = ((size_t)(b * C_ + g * CPG_)) * HW_;
    const float4* in4 = (const float4*)(in + base);
    int t = threadIdx.x;

    float s = 0.f, ss = 0.f;
    for (int i = t; i < N / 4; i += 1024) {
        float4 v = in4[i];
        s  += v.x + v.y + v.z + v.w;
        ss += v.x * v.x + v.y * v.y + v.z * v.z + v.w * v.w;
    }
    #pragma unroll
    for (int off = 32; off > 0; off >>= 1) {
        s  += __shfl_down(s, off, 64);
        ss += __shfl_down(ss, off, 64);
    }
    __shared__ float red[32];
    __shared__ float sh_rs, sh_m;
    int wid = t >> 6;
    if ((t & 63) == 0) { red[wid] = s; red[16 + wid] = ss; }
    __syncthreads();
    if (t == 0) {
        float S = 0.f, SS = 0.f;
        #pragma unroll
        for (int i = 0; i < 16; ++i) { S += red[i]; SS += red[16 + i]; }
        float m = S / (float)N;
        float var = SS / (float)N - m * m;
        sh_rs = rsqrtf(var + 1e-5f);
        sh_m = m;
    }
    __syncthreads();
    float rs = sh_rs, m = sh_m;
    short4v* out4 = (short4v*)(outb + base);
    for (int i = t; i < N / 4; i += 1024) {
        int ch = g * CPG_ + (i >> 10);
        float ga = gamma[ch] * rs;
        float be = beta[ch] - m * ga;
        float4 v = in4[i];
        short4v o;
        o.x = f2bf(fmaxf(fmaf(v.x, ga, be), 0.f));
        o.y = f2bf(fmaxf(fmaf(v.y, ga, be), 0.f));
        o.z = f2bf(fmaxf(fmaf(v.z, ga, be), 0.f));
        o.w = f2bf(fmaxf(fmaf(v.w, ga, be), 0.f));
        out4[i] = o;
    }
}

// ---------------------------------------------------------------------------
// K2: depthwise 7x7 SAME conv, bf16 [C][HW] in -> bf16 [C][HW] out
// ---------------------------------------------------------------------------
__global__ __launch_bounds__(256) void dw7_kernel(
    const short* __restrict__ in, const float* __restrict__ dwk,
    short* __restrict__ out)
{
    int plane = blockIdx.x;
    int c = plane & (C_ - 1);
    const short* src = in + (size_t)plane * HW_;
    short* dst = out + (size_t)plane * HW_;
    __shared__ float tile[70 * 72];
    __shared__ float wk[49];
    int t = threadIdx.x;
    if (t < 49) wk[t] = dwk[c * 49 + t];
    for (int i = t; i < 70 * 72; i += 256) tile[i] = 0.f;
    __syncthreads();
    const short4v* src4 = (const short4v*)src;
    for (int i = t; i < HW_ / 4; i += 256) {
        short4v v = src4[i];
        int y = i >> 4, x = (i & 15) * 4;
        float* tp = &tile[(y + 3) * 72 + (x + 3)];
        tp[0] = bf2f(v.x); tp[1] = bf2f(v.y);
        tp[2] = bf2f(v.z); tp[3] = bf2f(v.w);
    }
    __syncthreads();
    #pragma unroll
    for (int it = 0; it < 4; ++it) {
        int idx = it * 256 + t;
        int y = idx >> 4;                 // 0..63
        int x0 = (idx & 15) * 4;          // 0..60
        float a0 = 0.f, a1 = 0.f, a2 = 0.f, a3 = 0.f;
        #pragma unroll
        for (int dy = 0; dy < 7; ++dy) {
            const float* tr = &tile[(y + dy) * 72 + x0];
            float4 ra = *(const float4*)tr;
            float4 rb = *(const float4*)(tr + 4);
            float4 rc = *(const float4*)(tr + 8);
            float r[12] = {ra.x, ra.y, ra.z, ra.w,
                           rb.x, rb.y, rb.z, rb.w,
                           rc.x, rc.y, rc.z, rc.w};
            const float* wr = &wk[dy * 7];
            #pragma unroll
            for (int dx = 0; dx < 7; ++dx) {
                float wv = wr[dx];
                a0 = fmaf(r[dx], wv, a0);
                a1 = fmaf(r[dx + 1], wv, a1);
                a2 = fmaf(r[dx + 2], wv, a2);
                a3 = fmaf(r[dx + 3], wv, a3);
            }
        }
        short4v o;
        o.x = f2bf(a0); o.y = f2bf(a1); o.z = f2bf(a2); o.w = f2bf(a3);
        *(short4v*)&dst[y * 64 + x0] = o;
    }
}

// ---------------------------------------------------------------------------
// K2b: LDS-tiled transpose bf16 [C][HW] -> [HW][C], both tensors in one
// launch (blk<256: A, else B).
// ---------------------------------------------------------------------------
__global__ __launch_bounds__(256) void transpose2_kernel(
    const short* __restrict__ srcA, short* __restrict__ dstA,
    const short* __restrict__ srcB, short* __restrict__ dstB)
{
    int blk = blockIdx.x;                  // 0..511
    const short* src = (blk < 256) ? srcA : srcB;
    short*       dst = (blk < 256) ? dstA : dstB;
    int q = blk & 255;
    int b = q >> 6;
    int px0 = (q & 63) * 64;
    __shared__ unsigned ltile[64 * 132];   // 33 KB
    int t = threadIdx.x;
    const short* sb = src + (size_t)b * C_ * HW_;

    int pq4 = t & 15, cphi = t >> 4;
    #pragma unroll
    for (int i = 0; i < 8; ++i) {
        int cp = i * 16 + cphi;            // channel pair 0..127
        const short* r0 = sb + (size_t)(2 * cp) * HW_ + px0 + pq4 * 4;
        short4v lo = *(const short4v*)r0;
        short4v hi = *(const short4v*)(r0 + HW_);
        #pragma unroll
        for (int j = 0; j < 4; ++j) {
            int pl = pq4 * 4 + j;
            unsigned wrd = (unsigned)(unsigned short)lo[j]
                         | ((unsigned)(unsigned short)hi[j] << 16);
            ltile[pl * 132 + (cp ^ ((pl & 7) << 2))] = wrd;
        }
    }
    __syncthreads();

    int co = t & 31, ph = t >> 5;
    #pragma unroll
    for (int r = 0; r < 8; ++r) {
        int pl = r * 8 + ph;
        uint4 v = *(const uint4*)&ltile[pl * 132 + ((co * 4) ^ ((pl & 7) << 2))];
        *(uint4*)(dst + ((size_t)b * HW_ + px0 + pl) * C_ + co * 8) = v;
    }
}

// ---------------------------------------------------------------------------
// K3: pack weights. Blocks 0..4607: w1/w2 -> 32x32x16 A-fragment-major bf16.
// Fragment index f = (g*16 + cc16)*8 + ot ; element: lane holds
// A[o = ot*32 + (lane&31)][c = cc16*16 + (lane>>5)*8 + j].
// Blocks 4608..4671: pw1/pw2 -> 16x16x32 A-frags padded to 32 rows (unchanged).
// ---------------------------------------------------------------------------
__global__ __launch_bounds__(256) void wpack_all_kernel(
    const float* __restrict__ w1, const float* __restrict__ w2,
    const float* __restrict__ pw1, const float* __restrict__ pw2,
    short* __restrict__ wp1, short* __restrict__ wp2,
    short* __restrict__ ppk1, short* __restrict__ ppk2)
{
    int blk = blockIdx.x;
    if (blk < 4608) {
        const float* w = (blk < 2304) ? w1 : w2;
        short* wp = (blk < 2304) ? wp1 : wp2;
        int idx = (blk % 2304) * 256 + threadIdx.x;
        int j    = idx & 7;
        int lane = (idx >> 3) & 63;
        int ot   = (idx >> 9) & 7;                   // o-tile 0..7 (32 rows)
        int slab = idx >> 12;                        // 0..143 = g*16 + cc16
        int g = slab >> 4, cc16 = slab & 15;
        int o = ot * 32 + (lane & 31);
        int c = cc16 * 16 + (lane >> 5) * 8 + j;
        wp[idx] = f2bf(w[(size_t)(o * C_ + c) * KK_ + g]);
    } else {
        int q = blk - 4608;                          // 0..63
        const float* pw = (q < 32) ? pw1 : pw2;
        short* ppk = (q < 32) ? ppk1 : ppk2;
        int idx = (q & 31) * 256 + threadIdx.x;      // 0..8191
        int j = idx & 7, lane = (idx >> 3) & 63;
        int ot = (idx >> 9) & 1, sl = idx >> 10;     // 0..7
        int o = ot * 16 + (lane & 15);
        int k = sl * 32 + (lane >> 4) * 8 + j;
        ppk[idx] = (o < NOFF_) ? f2bf(pw[o * C_ + k]) : (short)0;
    }
}

// ---------------------------------------------------------------------------
// K4: fused deformable layer, channel-split. Grid 512 = (chalf, b, row),
// 512 threads (8 waves). Each block handles K-channels [chalf*128, +128) for
// one output row and atomically accumulates fp32 partial sums into outf
// (pre-zeroed). chalf==0 additionally adds bias (+resid).
// Einsum uses mfma_f32_32x32x16_bf16: wave wv owns o-tile [wv*32, +32) for
// both 32-px tiles -> each A-frag feeds 2 MFMAs, LDS B-reads halved vs 16x16.
// ---------------------------------------------------------------------------
__global__ __launch_bounds__(512, 4) void deform_fused_kernel(
    const short* __restrict__ ht,   const short* __restrict__ fdw,
    const short* __restrict__ ppk,  const float* __restrict__ pwb,
    const short* __restrict__ wp,   const float* __restrict__ bias,
    const float* __restrict__ resid, float* __restrict__ outf)
{
    int blk = blockIdx.x;
    int chalf = blk >> 8;                  // 0..1
    int qb = blk & 255;
    int b = qb >> 6;
    int row = qb & 63;
    __shared__ int   i00[576], i01[576], i10[576], i11[576];
    __shared__ float c00[576], c01[576], c10[576], c11[576];
    __shared__ __align__(16) short sbuf[2][8192];    // 2 x 16KB
    float* off_lds = (float*)&sbuf[0][0];            // 18*64 floats, dead before sbuf use
    int t = threadIdx.x;
    int wv = t >> 6, lane = t & 63;
    int pq = lane >> 4, pr = lane & 15;
    int l31 = lane & 31, hi = lane >> 5;

    // ---- stage A: pw offsets via 16x16x32 MFMA (all 8 waves; full C) ----
    {
        int ot = wv & 1, ptw = wv >> 1;
        int px = ptw * 16 + pr;
        const short8* fb8 = (const short8*)(fdw +
            ((size_t)b * HW_ + row * 64 + px) * C_);
        const short8* ap = (const short8*)ppk;
        floatx4 pacc = (floatx4){0.f, 0.f, 0.f, 0.f};
        #pragma unroll
        for (int sl = 0; sl < 8; ++sl) {
            short8 af = ap[(sl * 2 + ot) * 64 + lane];
            short8 bf = fb8[sl * 4 + pq];
            pacc = __builtin_amdgcn_mfma_f32_16x16x32_bf16(af, bf, pacc, 0, 0, 0);
        }
        #pragma unroll
        for (int r = 0; r < 4; ++r) {
            int o = ot * 16 + pq * 4 + r;
            if (o < NOFF_) off_lds[o * 64 + px] = pacc[r] + pwb[o];
        }
    }
    __syncthreads();

    // ---- stage B: bilinear coefficient tables (576 entries, 512 threads) ----
    for (int e = t; e < 576; e += 512) {
        int k = e >> 6, p = e & 63;
        float offy = off_lds[(2 * k) * 64 + p];
        float offx = off_lds[(2 * k + 1) * 64 + p];
        float py = (float)row + (float)(k / 3 - 1) + offy;
        float px = (float)p   + (float)(k % 3 - 1) + offx;
        float y0f = floorf(py), x0f = floorf(px);
        float wy1 = py - y0f, wx1 = px - x0f;
        float wy0 = 1.f - wy1, wx0 = 1.f - wx1;
        float y1f = y0f + 1.f, x1f = x0f + 1.f;
        bool vy0 = (y0f >= 0.f) && (y0f <= 63.f);
        bool vy1 = (y1f >= 0.f) && (y1f <= 63.f);
        bool vx0 = (x0f >= 0.f) && (x0f <= 63.f);
        bool vx1 = (x1f >= 0.f) && (x1f <= 63.f);
        int iy0 = (int)fminf(fmaxf(y0f, 0.f), 63.f);
        int iy1 = (int)fminf(fmaxf(y1f, 0.f), 63.f);
        int ix0 = (int)fminf(fmaxf(x0f, 0.f), 63.f);
        int ix1 = (int)fminf(fmaxf(x1f, 0.f), 63.f);
        i00[e] = iy0 * 64 + ix0; i01[e] = iy0 * 64 + ix1;
        i10[e] = iy1 * 64 + ix0; i11[e] = iy1 * 64 + ix1;
        c00[e] = (vy0 && vx0) ? wy0 * wx0 : 0.f;
        c01[e] = (vy0 && vx1) ? wy0 * wx1 : 0.f;
        c10[e] = (vy1 && vx0) ? wy1 * wx0 : 0.f;
        c11[e] = (vy1 && vx1) ? wy1 * wx1 : 0.f;
    }
    __syncthreads();

    // ---- stage C: 9 taps, this block's 128 channels, double-buffered ----
    // thread map: c8a = t&7 (channel octet; also does c8a+8), spx = t>>3.
    int c8a = t & 7;
    int spx = t >> 3;                       // 0..63
    const short* hb = ht + ((size_t)b * HW_) * C_ + chalf * 128;
    const short* hb0 = hb + c8a * 8;
    const short* hb1 = hb + c8a * 8 + 64;
    // LDS slot swizzle: slot = c8 ^ (px & 15); conflict-free writes & reads.
    int slotA = (c8a ^ (spx & 15)) * 8;
    int slotB = ((c8a + 8) ^ (spx & 15)) * 8;
    int srow = spx * 128;

    short8 ra[4], rb[4];
    auto prefetch = [&](int g) {
        int e = g * 64 + spx;
        int a00 = i00[e], a01 = i01[e], a10 = i10[e], a11 = i11[e];
        ra[0] = *(const short8*)(hb0 + (size_t)a00 * C_);
        ra[1] = *(const short8*)(hb0 + (size_t)a01 * C_);
        ra[2] = *(const short8*)(hb0 + (size_t)a10 * C_);
        ra[3] = *(const short8*)(hb0 + (size_t)a11 * C_);
        rb[0] = *(const short8*)(hb1 + (size_t)a00 * C_);
        rb[1] = *(const short8*)(hb1 + (size_t)a01 * C_);
        rb[2] = *(const short8*)(hb1 + (size_t)a10 * C_);
        rb[3] = *(const short8*)(hb1 + (size_t)a11 * C_);
    };
    auto stage_write = [&](int g, int bi) {
        int e = g * 64 + spx;
        float w00 = c00[e], w01 = c01[e], w10 = c10[e], w11 = c11[e];
        uint4 va, vb;
        float f0, f1;
        #define BLEND(R, J) (w00 * bf2f(R[0][J]) + w01 * bf2f(R[1][J]) \
                           + w10 * bf2f(R[2][J]) + w11 * bf2f(R[3][J]))
        f0 = BLEND(ra, 0); f1 = BLEND(ra, 1); va.x = pkbf(f0, f1);
        f0 = BLEND(ra, 2); f1 = BLEND(ra, 3); va.y = pkbf(f0, f1);
        f0 = BLEND(ra, 4); f1 = BLEND(ra, 5); va.z = pkbf(f0, f1);
        f0 = BLEND(ra, 6); f1 = BLEND(ra, 7); va.w = pkbf(f0, f1);
        f0 = BLEND(rb, 0); f1 = BLEND(rb, 1); vb.x = pkbf(f0, f1);
        f0 = BLEND(rb, 2); f1 = BLEND(rb, 3); vb.y = pkbf(f0, f1);
        f0 = BLEND(rb, 4); f1 = BLEND(rb, 5); vb.z = pkbf(f0, f1);
        f0 = BLEND(rb, 6); f1 = BLEND(rb, 7); vb.w = pkbf(f0, f1);
        #undef BLEND
        *(uint4*)&sbuf[bi][srow + slotA] = va;
        *(uint4*)&sbuf[bi][srow + slotB] = vb;
    };

    floatx16 acc[2];
    #pragma unroll
    for (int i = 0; i < 16; ++i) { acc[0][i] = 0.f; acc[1][i] = 0.f; }

    prefetch(0);
    stage_write(0, 0);
    prefetch(1);
    __syncthreads();

    const short8* wp8 = (const short8*)wp;
    int base0 = l31 * 128;                 // px tile 0
    int base1 = (32 + l31) * 128;          // px tile 1 (same low-4 px bits)
    int msk = l31 & 15;

    for (int g = 0; g < 9; ++g) {
        const short* sb = sbuf[g & 1];
        #pragma unroll
        for (int kh = 0; kh < 2; ++kh) {
            short8 af[4];
            #pragma unroll
            for (int qq = 0; qq < 4; ++qq)
                af[qq] = wp8[(size_t)(((g * 16 + chalf * 8 + kh * 4 + qq) * 8 + wv) * 64 + lane)];
            #pragma unroll
            for (int qq = 0; qq < 4; ++qq) {
                int ks = kh * 4 + qq;
                int so = ((((ks << 1) | hi) ^ msk) << 3);
                short8 b0 = *(const short8*)&sb[base0 + so];
                short8 b1 = *(const short8*)&sb[base1 + so];
                acc[0] = __builtin_amdgcn_mfma_f32_32x32x16_bf16(af[qq], b0, acc[0], 0, 0, 0);
                acc[1] = __builtin_amdgcn_mfma_f32_32x32x16_bf16(af[qq], b1, acc[1], 0, 0, 0);
            }
        }
        if (g + 1 < 9) {
            stage_write(g + 1, (g + 1) & 1);
            if (g + 2 < 9) prefetch(g + 2);
        }
        __syncthreads();
    }

    // ---- epilogue: atomic fp32 partial-sum accumulate ----
    // C/D 32x32: col = lane&31 (px), row = (r&3) + 8*(r>>2) + 4*hi (o)
    #pragma unroll
    for (int r = 0; r < 16; ++r) {
        int o = wv * 32 + (r & 3) + 8 * (r >> 2) + 4 * hi;
        float v0 = acc[0][r], v1 = acc[1][r];
        size_t ob = ((size_t)(b * C_ + o)) * HW_ + row * 64 + l31;
        if (chalf == 0) {
            float bo = bias[o];
            v0 += bo; v1 += bo;
            if (resid) { v0 += resid[ob]; v1 += resid[ob + 32]; }
        }
        atomicAdd(&outf[ob], v0);
        atomicAdd(&outf[ob + 32], v1);
    }
}

// ---------------------------------------------------------------------------
extern "C" void kernel_launch(void* const* d_in, const int* in_sizes, int n_in,
                              void* d_out, int out_size, void* d_ws, size_t ws_size,
                              hipStream_t stream)
{
    const float* x     = (const float*)d_in[0];
    const float* gn1_g = (const float*)d_in[1];
    const float* gn1_b = (const float*)d_in[2];
    const float* dw1   = (const float*)d_in[3];
    const float* pw1   = (const float*)d_in[4];
    const float* pwb1  = (const float*)d_in[5];
    const float* w1    = (const float*)d_in[6];
    const float* b1    = (const float*)d_in[7];
    const float* gn2_g = (const float*)d_in[8];
    const float* gn2_b = (const float*)d_in[9];
    const float* dw2   = (const float*)d_in[10];
    const float* pw2   = (const float*)d_in[11];
    const float* pwb2  = (const float*)d_in[12];
    const float* w2    = (const float*)d_in[13];
    const float* b2    = (const float*)d_in[14];
    float* out = (float*)d_out;

    float* ws   = (float*)d_ws;
    // (ws + 0 .. 2097152) previously y1b -- now unused (y1 fp32 lives in d_out)
    short* hbf  = (short*)(ws + 2097152);      // bf16 [B][C][HW]  (8 MB)
    short* hbt  = (short*)(ws + 4194304);      // bf16 [B][HW][C]  (8 MB)
    short* fdwc = (short*)(ws + 6291456);      // bf16 [B][C][HW]  (8 MB)
    short* fdwt = (short*)(ws + 8388608);      // bf16 [B][HW][C]  (8 MB)
    short* wp1  = (short*)(ws + 10485760);     // 589,824 bf16
    short* wp2  = (short*)(ws + 10780672);     // 589,824 bf16
    short* ppk1 = (short*)(ws + 11075584);     // 8,192 bf16
    short* ppk2 = (short*)(ws + 11079680);     // 8,192 bf16

    const size_t OUTBYTES = (size_t)B_ * C_ * HW_ * sizeof(float);  // 16.78 MB

    wpack_all_kernel<<<4672, 256, 0, stream>>>(w1, w2, pw1, pw2,
                                               wp1, wp2, ppk1, ppk2);

    // layer 1 (y1 accumulates fp32 in d_out)
    hipMemsetAsync(d_out, 0, OUTBYTES, stream);
    gn_relu_f32_kernel<<<B_ * NG_, 1024, 0, stream>>>(x, gn1_g, gn1_b, hbf);
    dw7_kernel<<<B_ * C_, 256, 0, stream>>>(hbf, dw1, fdwc);
    transpose2_kernel<<<512, 256, 0, stream>>>(hbf, hbt, fdwc, fdwt);
    deform_fused_kernel<<<512, 512, 0, stream>>>(
        hbt, fdwt, ppk1, pwb1, wp1, b1, nullptr, out);

    // layer 2 (+ residual x); gn2 consumes y1 (=out) BEFORE out is re-zeroed
    gn_relu_f32_kernel<<<B_ * NG_, 1024, 0, stream>>>(out, gn2_g, gn2_b, hbf);
    dw7_kernel<<<B_ * C_, 256, 0, stream>>>(hbf, dw2, fdwc);
    transpose2_kernel<<<512, 256, 0, stream>>>(hbf, hbt, fdwc, fdwt);
    hipMemsetAsync(d_out, 0, OUTBYTES, stream);
    deform_fused_kernel<<<512, 512, 0, stream>>>(
        hbt, fdwt, ppk2, pwb2, wp2, b2, x, out);
}

// Round 2
// 249.064 us; speedup vs baseline: 1.1490x; 1.1490x over previous
//
#include <hip/hip_runtime.h>

#define B_    4
#define C_    256
#define H_    64
#define W_    64
#define HW_   4096
#define NG_   32
#define CPG_  8
#define KK_   9
#define NOFF_ 18

typedef __attribute__((ext_vector_type(8))) short short8;
typedef __attribute__((ext_vector_type(4))) short short4v;
typedef __attribute__((ext_vector_type(4))) float floatx4;
typedef __attribute__((ext_vector_type(16))) float floatx16;

static __device__ __forceinline__ short f2bf(float f) {
    union { float f; unsigned u; } v; v.f = f;
    unsigned r = v.u + 0x7fff + ((v.u >> 16) & 1);   // RNE
    return (short)(r >> 16);
}
static __device__ __forceinline__ float bf2f(short s) {
    union { unsigned u; float f; } v;
    v.u = ((unsigned)(unsigned short)s) << 16;
    return v.f;
}
// packed f32x2 -> bf16x2 (RNE), single VALU op
static __device__ __forceinline__ unsigned pkbf(float lo, float hi) {
    unsigned r;
    asm("v_cvt_pk_bf16_f32 %0, %1, %2" : "=v"(r) : "v"(lo), "v"(hi));
    return r;
}

// ---------------------------------------------------------------------------
// K1: GroupNorm (32 groups) + ReLU -> bf16 [C][HW]. fp32-input variant.
// ---------------------------------------------------------------------------
__global__ __launch_bounds__(1024) void gn_relu_f32_kernel(
    const float* __restrict__ in, const float* __restrict__ gamma,
    const float* __restrict__ beta, short* __restrict__ outb)
{
    int b = blockIdx.x >> 5;
    int g = blockIdx.x & 31;
    const int N = CPG_ * HW_;              // 32768
    size_t base = ((size_t)(b * C_ + g * CPG_)) * HW_;
    const float4* in4 = (const float4*)(in + base);
    int t = threadIdx.x;

    float s = 0.f, ss = 0.f;
    for (int i = t; i < N / 4; i += 1024) {
        float4 v = in4[i];
        s  += v.x + v.y + v.z + v.w;
        ss += v.x * v.x + v.y * v.y + v.z * v.z + v.w * v.w;
    }
    #pragma unroll
    for (int off = 32; off > 0; off >>= 1) {
        s  += __shfl_down(s, off, 64);
        ss += __shfl_down(ss, off, 64);
    }
    __shared__ float red[32];
    __shared__ float sh_rs, sh_m;
    int wid = t >> 6;
    if ((t & 63) == 0) { red[wid] = s; red[16 + wid] = ss; }
    __syncthreads();
    if (t == 0) {
        float S = 0.f, SS = 0.f;
        #pragma unroll
        for (int i = 0; i < 16; ++i) { S += red[i]; SS += red[16 + i]; }
        float m = S / (float)N;
        float var = SS / (float)N - m * m;
        sh_rs = rsqrtf(var + 1e-5f);
        sh_m = m;
    }
    __syncthreads();
    float rs = sh_rs, m = sh_m;
    short4v* out4 = (short4v*)(outb + base);
    for (int i = t; i < N / 4; i += 1024) {
        int ch = g * CPG_ + (i >> 10);
        float ga = gamma[ch] * rs;
        float be = beta[ch] - m * ga;
        float4 v = in4[i];
        short4v o;
        o.x = f2bf(fmaxf(fmaf(v.x, ga, be), 0.f));
        o.y = f2bf(fmaxf(fmaf(v.y, ga, be), 0.f));
        o.z = f2bf(fmaxf(fmaf(v.z, ga, be), 0.f));
        o.w = f2bf(fmaxf(fmaf(v.w, ga, be), 0.f));
        out4[i] = o;
    }
}

// bf16-input variant (reads layer-1 output y1 in bf16)
__global__ __launch_bounds__(1024) void gn_relu_bf16_kernel(
    const short* __restrict__ in, const float* __restrict__ gamma,
    const float* __restrict__ beta, short* __restrict__ outb)
{
    int b = blockIdx.x >> 5;
    int g = blockIdx.x & 31;
    const int N = CPG_ * HW_;
    size_t base = ((size_t)(b * C_ + g * CPG_)) * HW_;
    const short4v* in4 = (const short4v*)(in + base);
    int t = threadIdx.x;

    float s = 0.f, ss = 0.f;
    for (int i = t; i < N / 4; i += 1024) {
        short4v sv = in4[i];
        float vx = bf2f(sv.x), vy = bf2f(sv.y), vz = bf2f(sv.z), vw = bf2f(sv.w);
        s  += vx + vy + vz + vw;
        ss += vx * vx + vy * vy + vz * vz + vw * vw;
    }
    #pragma unroll
    for (int off = 32; off > 0; off >>= 1) {
        s  += __shfl_down(s, off, 64);
        ss += __shfl_down(ss, off, 64);
    }
    __shared__ float red[32];
    __shared__ float sh_rs, sh_m;
    int wid = t >> 6;
    if ((t & 63) == 0) { red[wid] = s; red[16 + wid] = ss; }
    __syncthreads();
    if (t == 0) {
        float S = 0.f, SS = 0.f;
        #pragma unroll
        for (int i = 0; i < 16; ++i) { S += red[i]; SS += red[16 + i]; }
        float m = S / (float)N;
        float var = SS / (float)N - m * m;
        sh_rs = rsqrtf(var + 1e-5f);
        sh_m = m;
    }
    __syncthreads();
    float rs = sh_rs, m = sh_m;
    short4v* out4 = (short4v*)(outb + base);
    for (int i = t; i < N / 4; i += 1024) {
        int ch = g * CPG_ + (i >> 10);
        float ga = gamma[ch] * rs;
        float be = beta[ch] - m * ga;
        short4v sv = in4[i];
        short4v o;
        o.x = f2bf(fmaxf(fmaf(bf2f(sv.x), ga, be), 0.f));
        o.y = f2bf(fmaxf(fmaf(bf2f(sv.y), ga, be), 0.f));
        o.z = f2bf(fmaxf(fmaf(bf2f(sv.z), ga, be), 0.f));
        o.w = f2bf(fmaxf(fmaf(bf2f(sv.w), ga, be), 0.f));
        out4[i] = o;
    }
}

// ---------------------------------------------------------------------------
// K2: depthwise 7x7 SAME conv, bf16 [C][HW] in -> bf16 [C][HW] out
// ---------------------------------------------------------------------------
__global__ __launch_bounds__(256) void dw7_kernel(
    const short* __restrict__ in, const float* __restrict__ dwk,
    short* __restrict__ out)
{
    int plane = blockIdx.x;
    int c = plane & (C_ - 1);
    const short* src = in + (size_t)plane * HW_;
    short* dst = out + (size_t)plane * HW_;
    __shared__ float tile[70 * 72];
    __shared__ float wk[49];
    int t = threadIdx.x;
    if (t < 49) wk[t] = dwk[c * 49 + t];
    for (int i = t; i < 70 * 72; i += 256) tile[i] = 0.f;
    __syncthreads();
    const short4v* src4 = (const short4v*)src;
    for (int i = t; i < HW_ / 4; i += 256) {
        short4v v = src4[i];
        int y = i >> 4, x = (i & 15) * 4;
        float* tp = &tile[(y + 3) * 72 + (x + 3)];
        tp[0] = bf2f(v.x); tp[1] = bf2f(v.y);
        tp[2] = bf2f(v.z); tp[3] = bf2f(v.w);
    }
    __syncthreads();
    #pragma unroll
    for (int it = 0; it < 4; ++it) {
        int idx = it * 256 + t;
        int y = idx >> 4;                 // 0..63
        int x0 = (idx & 15) * 4;          // 0..60
        float a0 = 0.f, a1 = 0.f, a2 = 0.f, a3 = 0.f;
        #pragma unroll
        for (int dy = 0; dy < 7; ++dy) {
            const float* tr = &tile[(y + dy) * 72 + x0];
            float4 ra = *(const float4*)tr;
            float4 rb = *(const float4*)(tr + 4);
            float4 rc = *(const float4*)(tr + 8);
            float r[12] = {ra.x, ra.y, ra.z, ra.w,
                           rb.x, rb.y, rb.z, rb.w,
                           rc.x, rc.y, rc.z, rc.w};
            const float* wr = &wk[dy * 7];
            #pragma unroll
            for (int dx = 0; dx < 7; ++dx) {
                float wv = wr[dx];
                a0 = fmaf(r[dx], wv, a0);
                a1 = fmaf(r[dx + 1], wv, a1);
                a2 = fmaf(r[dx + 2], wv, a2);
                a3 = fmaf(r[dx + 3], wv, a3);
            }
        }
        short4v o;
        o.x = f2bf(a0); o.y = f2bf(a1); o.z = f2bf(a2); o.w = f2bf(a3);
        *(short4v*)&dst[y * 64 + x0] = o;
    }
}

// ---------------------------------------------------------------------------
// K2b: LDS-tiled transpose bf16 [C][HW] -> [HW][C], both tensors in one
// launch (blk<256: A, else B).
// ---------------------------------------------------------------------------
__global__ __launch_bounds__(256) void transpose2_kernel(
    const short* __restrict__ srcA, short* __restrict__ dstA,
    const short* __restrict__ srcB, short* __restrict__ dstB)
{
    int blk = blockIdx.x;                  // 0..511
    const short* src = (blk < 256) ? srcA : srcB;
    short*       dst = (blk < 256) ? dstA : dstB;
    int q = blk & 255;
    int b = q >> 6;
    int px0 = (q & 63) * 64;
    __shared__ unsigned ltile[64 * 132];   // 33 KB
    int t = threadIdx.x;
    const short* sb = src + (size_t)b * C_ * HW_;

    int pq4 = t & 15, cphi = t >> 4;
    #pragma unroll
    for (int i = 0; i < 8; ++i) {
        int cp = i * 16 + cphi;            // channel pair 0..127
        const short* r0 = sb + (size_t)(2 * cp) * HW_ + px0 + pq4 * 4;
        short4v lo = *(const short4v*)r0;
        short4v hi = *(const short4v*)(r0 + HW_);
        #pragma unroll
        for (int j = 0; j < 4; ++j) {
            int pl = pq4 * 4 + j;
            unsigned wrd = (unsigned)(unsigned short)lo[j]
                         | ((unsigned)(unsigned short)hi[j] << 16);
            ltile[pl * 132 + (cp ^ ((pl & 7) << 2))] = wrd;
        }
    }
    __syncthreads();

    int co = t & 31, ph = t >> 5;
    #pragma unroll
    for (int r = 0; r < 8; ++r) {
        int pl = r * 8 + ph;
        uint4 v = *(const uint4*)&ltile[pl * 132 + ((co * 4) ^ ((pl & 7) << 2))];
        *(uint4*)(dst + ((size_t)b * HW_ + px0 + pl) * C_ + co * 8) = v;
    }
}

// ---------------------------------------------------------------------------
// K3: pack weights. Blocks 0..4607: w1/w2 -> 32x32x16 A-fragment-major bf16.
// Fragment f = (g*16 + cc16)*8 + ot ; lane holds
// A[o = ot*32 + (lane&31)][c = cc16*16 + (lane>>5)*8 + j].
// Blocks 4608..4671: pw1/pw2 -> 16x16x32 A-frags padded to 32 rows.
// ---------------------------------------------------------------------------
__global__ __launch_bounds__(256) void wpack_all_kernel(
    const float* __restrict__ w1, const float* __restrict__ w2,
    const float* __restrict__ pw1, const float* __restrict__ pw2,
    short* __restrict__ wp1, short* __restrict__ wp2,
    short* __restrict__ ppk1, short* __restrict__ ppk2)
{
    int blk = blockIdx.x;
    if (blk < 4608) {
        const float* w = (blk < 2304) ? w1 : w2;
        short* wp = (blk < 2304) ? wp1 : wp2;
        int idx = (blk % 2304) * 256 + threadIdx.x;
        int j    = idx & 7;
        int lane = (idx >> 3) & 63;
        int ot   = (idx >> 9) & 7;                   // o-tile 0..7 (32 rows)
        int slab = idx >> 12;                        // 0..143 = g*16 + cc16
        int g = slab >> 4, cc16 = slab & 15;
        int o = ot * 32 + (lane & 31);
        int c = cc16 * 16 + (lane >> 5) * 8 + j;
        wp[idx] = f2bf(w[(size_t)(o * C_ + c) * KK_ + g]);
    } else {
        int q = blk - 4608;                          // 0..63
        const float* pw = (q < 32) ? pw1 : pw2;
        short* ppk = (q < 32) ? ppk1 : ppk2;
        int idx = (q & 31) * 256 + threadIdx.x;      // 0..8191
        int j = idx & 7, lane = (idx >> 3) & 63;
        int ot = (idx >> 9) & 1, sl = idx >> 10;     // 0..7
        int o = ot * 16 + (lane & 15);
        int k = sl * 32 + (lane >> 4) * 8 + j;
        ppk[idx] = (o < NOFF_) ? f2bf(pw[o * C_ + k]) : (short)0;
    }
}

// ---------------------------------------------------------------------------
// K4: fused deformable layer. One block (1024 thr = 16 waves) per (b,row),
// full C. Einsum uses mfma_f32_32x32x16_bf16 with conflict-free LDS swizzle.
// K-split wave pairs: waves (wv, wv+8) each handle 128 channels for o-tile
// (wv&7), both 32-px tiles; partials combined in LDS (no atomics).
// ---------------------------------------------------------------------------
__global__ __launch_bounds__(1024, 4) void deform_fused_kernel(
    const short* __restrict__ ht,   const short* __restrict__ fdw,
    const short* __restrict__ ppk,  const float* __restrict__ pwb,
    const short* __restrict__ wp,   const float* __restrict__ bias,
    const float* __restrict__ resid, float* __restrict__ outf,
    short* __restrict__ outb)
{
    int b = blockIdx.x >> 6;
    int row = blockIdx.x & 63;
    __shared__ int   i00[576], i01[576], i10[576], i11[576];
    __shared__ float c00[576], c01[576], c10[576], c11[576];
    __shared__ __align__(16) short sbuf[2][2][8192];  // [buf][panel][64px*128ch] = 64KB
    float* off_lds = (float*)&sbuf[0][0][0];          // 18*64 floats, dead before staging
    int t = threadIdx.x;
    int wv = t >> 6, lane = t & 63;
    int pq = lane >> 4, pr = lane & 15;
    int l31 = lane & 31, hi = lane >> 5;

    // ---- stage A: pw offsets via 16x16x32 MFMA (waves 0..7, full C) ----
    if (wv < 8) {
        int ot = wv & 1, ptw = wv >> 1;
        int px = ptw * 16 + pr;
        const short8* fb8 = (const short8*)(fdw +
            ((size_t)b * HW_ + row * 64 + px) * C_);
        const short8* ap = (const short8*)ppk;
        floatx4 pacc = (floatx4){0.f, 0.f, 0.f, 0.f};
        #pragma unroll
        for (int sl = 0; sl < 8; ++sl) {
            short8 af = ap[(sl * 2 + ot) * 64 + lane];
            short8 bf = fb8[sl * 4 + pq];
            pacc = __builtin_amdgcn_mfma_f32_16x16x32_bf16(af, bf, pacc, 0, 0, 0);
        }
        #pragma unroll
        for (int r = 0; r < 4; ++r) {
            int o = ot * 16 + pq * 4 + r;
            if (o < NOFF_) off_lds[o * 64 + px] = pacc[r] + pwb[o];
        }
    }
    __syncthreads();

    // ---- stage B: bilinear coefficient tables ----
    if (t < 576) {
        int e = t;
        int k = e >> 6, p = e & 63;
        float offy = off_lds[(2 * k) * 64 + p];
        float offx = off_lds[(2 * k + 1) * 64 + p];
        float py = (float)row + (float)(k / 3 - 1) + offy;
        float px = (float)p   + (float)(k % 3 - 1) + offx;
        float y0f = floorf(py), x0f = floorf(px);
        float wy1 = py - y0f, wx1 = px - x0f;
        float wy0 = 1.f - wy1, wx0 = 1.f - wx1;
        float y1f = y0f + 1.f, x1f = x0f + 1.f;
        bool vy0 = (y0f >= 0.f) && (y0f <= 63.f);
        bool vy1 = (y1f >= 0.f) && (y1f <= 63.f);
        bool vx0 = (x0f >= 0.f) && (x0f <= 63.f);
        bool vx1 = (x1f >= 0.f) && (x1f <= 63.f);
        int iy0 = (int)fminf(fmaxf(y0f, 0.f), 63.f);
        int iy1 = (int)fminf(fmaxf(y1f, 0.f), 63.f);
        int ix0 = (int)fminf(fmaxf(x0f, 0.f), 63.f);
        int ix1 = (int)fminf(fmaxf(x1f, 0.f), 63.f);
        i00[e] = iy0 * 64 + ix0; i01[e] = iy0 * 64 + ix1;
        i10[e] = iy1 * 64 + ix0; i11[e] = iy1 * 64 + ix1;
        c00[e] = (vy0 && vx0) ? wy0 * wx0 : 0.f;
        c01[e] = (vy0 && vx1) ? wy0 * wx1 : 0.f;
        c10[e] = (vy1 && vx0) ? wy1 * wx0 : 0.f;
        c11[e] = (vy1 && vx1) ? wy1 * wx1 : 0.f;
    }
    __syncthreads();

    // ---- stage C: 9 taps, full C, double-buffered ----
    // thread map: c8a = t&7 (octet), pan = (t>>3)&1 (128-ch panel), spx = t>>4.
    int c8a = t & 7;
    int pan = (t >> 3) & 1;
    int spx = t >> 4;                       // 0..63
    const short* hb = ht + ((size_t)b * HW_) * C_ + pan * 128 + c8a * 8;
    const short* hb0 = hb;                  // octet c8a of panel
    const short* hb1 = hb + 64;             // octet c8a+8 of panel
    // per-panel LDS slot swizzle: slot = oct ^ (px & 15); conflict-free.
    int slotA = (c8a ^ (spx & 15)) * 8;
    int slotB = ((c8a + 8) ^ (spx & 15)) * 8;
    int srow = spx * 128;

    short8 ra[4], rb[4];
    auto prefetch = [&](int g) {
        int e = g * 64 + spx;
        int a00 = i00[e], a01 = i01[e], a10 = i10[e], a11 = i11[e];
        ra[0] = *(const short8*)(hb0 + (size_t)a00 * C_);
        ra[1] = *(const short8*)(hb0 + (size_t)a01 * C_);
        ra[2] = *(const short8*)(hb0 + (size_t)a10 * C_);
        ra[3] = *(const short8*)(hb0 + (size_t)a11 * C_);
        rb[0] = *(const short8*)(hb1 + (size_t)a00 * C_);
        rb[1] = *(const short8*)(hb1 + (size_t)a01 * C_);
        rb[2] = *(const short8*)(hb1 + (size_t)a10 * C_);
        rb[3] = *(const short8*)(hb1 + (size_t)a11 * C_);
    };
    auto stage_write = [&](int g, int bi) {
        int e = g * 64 + spx;
        float w00 = c00[e], w01 = c01[e], w10 = c10[e], w11 = c11[e];
        uint4 va, vb;
        float f0, f1;
        #define BLEND(R, J) (w00 * bf2f(R[0][J]) + w01 * bf2f(R[1][J]) \
                           + w10 * bf2f(R[2][J]) + w11 * bf2f(R[3][J]))
        f0 = BLEND(ra, 0); f1 = BLEND(ra, 1); va.x = pkbf(f0, f1);
        f0 = BLEND(ra, 2); f1 = BLEND(ra, 3); va.y = pkbf(f0, f1);
        f0 = BLEND(ra, 4); f1 = BLEND(ra, 5); va.z = pkbf(f0, f1);
        f0 = BLEND(ra, 6); f1 = BLEND(ra, 7); va.w = pkbf(f0, f1);
        f0 = BLEND(rb, 0); f1 = BLEND(rb, 1); vb.x = pkbf(f0, f1);
        f0 = BLEND(rb, 2); f1 = BLEND(rb, 3); vb.y = pkbf(f0, f1);
        f0 = BLEND(rb, 4); f1 = BLEND(rb, 5); vb.z = pkbf(f0, f1);
        f0 = BLEND(rb, 6); f1 = BLEND(rb, 7); vb.w = pkbf(f0, f1);
        #undef BLEND
        short* sp = &sbuf[bi][pan][srow];
        *(uint4*)&sp[slotA] = va;
        *(uint4*)&sp[slotB] = vb;
    };

    // wave role: pairId = o-tile (32 rows), half = K-half (128 channels)
    int pairId = wv & 7;
    int half = wv >> 3;

    floatx16 acc[2];
    #pragma unroll
    for (int i = 0; i < 16; ++i) { acc[0][i] = 0.f; acc[1][i] = 0.f; }

    prefetch(0);
    stage_write(0, 0);
    prefetch(1);
    __syncthreads();

    const short8* wp8 = (const short8*)wp;
    int msk = l31 & 15;

    for (int g = 0; g < 9; ++g) {
        const short* sb = &sbuf[g & 1][half][0];
        #pragma unroll
        for (int q4 = 0; q4 < 2; ++q4) {
            short8 af[4];
            #pragma unroll
            for (int qq = 0; qq < 4; ++qq)
                af[qq] = wp8[(size_t)(((g * 16 + half * 8 + q4 * 4 + qq) * 8 + pairId) * 64 + lane)];
            #pragma unroll
            for (int qq = 0; qq < 4; ++qq) {
                int ksl = q4 * 4 + qq;                       // local slab 0..7
                int so = ((((ksl << 1) | hi) ^ msk) << 3);
                short8 b0 = *(const short8*)&sb[l31 * 128 + so];
                short8 b1 = *(const short8*)&sb[(32 + l31) * 128 + so];
                acc[0] = __builtin_amdgcn_mfma_f32_32x32x16_bf16(af[qq], b0, acc[0], 0, 0, 0);
                acc[1] = __builtin_amdgcn_mfma_f32_32x32x16_bf16(af[qq], b1, acc[1], 0, 0, 0);
            }
        }
        if (g + 1 < 9) {
            stage_write(g + 1, (g + 1) & 1);
            if (g + 2 < 9) prefetch(g + 2);
        }
        __syncthreads();
    }

    // ---- combine K-halves in LDS (lane-major planes, conflict-free) ----
    // wave wv (half=0) writes its pxt=1 partial; wv+8 (half=1) writes pxt=0.
    float* xch = (float*)&sbuf[0][0][0];     // 16 regions x 4KB = 64KB
    int wreg = (pairId * 2 + half) * 1024;   // floats
    floatx16 aw = half ? acc[0] : acc[1];
    floatx4* xq = (floatx4*)xch;
    #pragma unroll
    for (int j = 0; j < 4; ++j) {
        floatx4 v = {aw[j * 4 + 0], aw[j * 4 + 1], aw[j * 4 + 2], aw[j * 4 + 3]};
        xq[(wreg >> 2) + j * 64 + lane] = v;
    }
    __syncthreads();
    int rreg = (pairId * 2 + (half ^ 1)) * 1024;
    floatx16 ac = half ? acc[1] : acc[0];
    #pragma unroll
    for (int j = 0; j < 4; ++j) {
        floatx4 v = xq[(rreg >> 2) + j * 64 + lane];
        ac[j * 4 + 0] += v.x; ac[j * 4 + 1] += v.y;
        ac[j * 4 + 2] += v.z; ac[j * 4 + 3] += v.w;
    }

    // ---- epilogue: wave stores its px-tile (pxt = half) ----
    // C/D 32x32: col = lane&31 (px), row = (r&3) + 8*(r>>2) + 4*hi (o)
    #pragma unroll
    for (int r = 0; r < 16; ++r) {
        int o = pairId * 32 + (r & 3) + 8 * (r >> 2) + 4 * hi;
        float v = ac[r] + bias[o];
        size_t ob = ((size_t)(b * C_ + o)) * HW_ + row * 64 + half * 32 + l31;
        if (outf) {
            if (resid) v += resid[ob];
            outf[ob] = v;
        } else {
            outb[ob] = f2bf(v);
        }
    }
}

// ---------------------------------------------------------------------------
extern "C" void kernel_launch(void* const* d_in, const int* in_sizes, int n_in,
                              void* d_out, int out_size, void* d_ws, size_t ws_size,
                              hipStream_t stream)
{
    const float* x     = (const float*)d_in[0];
    const float* gn1_g = (const float*)d_in[1];
    const float* gn1_b = (const float*)d_in[2];
    const float* dw1   = (const float*)d_in[3];
    const float* pw1   = (const float*)d_in[4];
    const float* pwb1  = (const float*)d_in[5];
    const float* w1    = (const float*)d_in[6];
    const float* b1    = (const float*)d_in[7];
    const float* gn2_g = (const float*)d_in[8];
    const float* gn2_b = (const float*)d_in[9];
    const float* dw2   = (const float*)d_in[10];
    const float* pw2   = (const float*)d_in[11];
    const float* pwb2  = (const float*)d_in[12];
    const float* w2    = (const float*)d_in[13];
    const float* b2    = (const float*)d_in[14];
    float* out = (float*)d_out;

    float* ws   = (float*)d_ws;
    short* y1b  = (short*)ws;                  // bf16 [B][C][HW]  (8 MB)
    short* hbf  = (short*)(ws + 2097152);      // bf16 [B][C][HW]  (8 MB)
    short* hbt  = (short*)(ws + 4194304);      // bf16 [B][HW][C]  (8 MB)
    short* fdwc = (short*)(ws + 6291456);      // bf16 [B][C][HW]  (8 MB)
    short* fdwt = (short*)(ws + 8388608);      // bf16 [B][HW][C]  (8 MB)
    short* wp1  = (short*)(ws + 10485760);     // 589,824 bf16
    short* wp2  = (short*)(ws + 10780672);     // 589,824 bf16
    short* ppk1 = (short*)(ws + 11075584);     // 8,192 bf16
    short* ppk2 = (short*)(ws + 11079680);     // 8,192 bf16

    wpack_all_kernel<<<4672, 256, 0, stream>>>(w1, w2, pw1, pw2,
                                               wp1, wp2, ppk1, ppk2);

    // layer 1
    gn_relu_f32_kernel<<<B_ * NG_, 1024, 0, stream>>>(x, gn1_g, gn1_b, hbf);
    dw7_kernel<<<B_ * C_, 256, 0, stream>>>(hbf, dw1, fdwc);
    transpose2_kernel<<<512, 256, 0, stream>>>(hbf, hbt, fdwc, fdwt);
    deform_fused_kernel<<<B_ * H_, 1024, 0, stream>>>(
        hbt, fdwt, ppk1, pwb1, wp1, b1, nullptr, nullptr, y1b);

    // layer 2 (+ residual x)
    gn_relu_bf16_kernel<<<B_ * NG_, 1024, 0, stream>>>(y1b, gn2_g, gn2_b, hbf);
    dw7_kernel<<<B_ * C_, 256, 0, stream>>>(hbf, dw2, fdwc);
    transpose2_kernel<<<512, 256, 0, stream>>>(hbf, hbt, fdwc, fdwt);
    deform_fused_kernel<<<B_ * H_, 1024, 0, stream>>>(
        hbt, fdwt, ppk2, pwb2, wp2, b2, x, out, nullptr);
}

// Round 3
// 246.387 us; speedup vs baseline: 1.1614x; 1.0109x over previous
//
#include <hip/hip_runtime.h>

#define B_    4
#define C_    256
#define H_    64
#define W_    64
#define HW_   4096
#define NG_   32
#define CPG_  8
#define KK_   9
#define NOFF_ 18

typedef __attribute__((ext_vector_type(8))) short short8;
typedef __attribute__((ext_vector_type(4))) short short4v;
typedef __attribute__((ext_vector_type(4))) float floatx4;
typedef __attribute__((ext_vector_type(16))) float floatx16;

static __device__ __forceinline__ short f2bf(float f) {
    union { float f; unsigned u; } v; v.f = f;
    unsigned r = v.u + 0x7fff + ((v.u >> 16) & 1);   // RNE
    return (short)(r >> 16);
}
static __device__ __forceinline__ float bf2f(short s) {
    union { unsigned u; float f; } v;
    v.u = ((unsigned)(unsigned short)s) << 16;
    return v.f;
}
// packed f32x2 -> bf16x2 (RNE), single VALU op
static __device__ __forceinline__ unsigned pkbf(float lo, float hi) {
    unsigned r;
    asm("v_cvt_pk_bf16_f32 %0, %1, %2" : "=v"(r) : "v"(lo), "v"(hi));
    return r;
}

// ---------------------------------------------------------------------------
// K1: GroupNorm (32 groups) + ReLU -> bf16 [C][HW]. fp32-input variant.
// ---------------------------------------------------------------------------
__global__ __launch_bounds__(1024) void gn_relu_f32_kernel(
    const float* __restrict__ in, const float* __restrict__ gamma,
    const float* __restrict__ beta, short* __restrict__ outb)
{
    int b = blockIdx.x >> 5;
    int g = blockIdx.x & 31;
    const int N = CPG_ * HW_;              // 32768
    size_t base = ((size_t)(b * C_ + g * CPG_)) * HW_;
    const float4* in4 = (const float4*)(in + base);
    int t = threadIdx.x;

    float s = 0.f, ss = 0.f;
    for (int i = t; i < N / 4; i += 1024) {
        float4 v = in4[i];
        s  += v.x + v.y + v.z + v.w;
        ss += v.x * v.x + v.y * v.y + v.z * v.z + v.w * v.w;
    }
    #pragma unroll
    for (int off = 32; off > 0; off >>= 1) {
        s  += __shfl_down(s, off, 64);
        ss += __shfl_down(ss, off, 64);
    }
    __shared__ float red[32];
    __shared__ float sh_rs, sh_m;
    int wid = t >> 6;
    if ((t & 63) == 0) { red[wid] = s; red[16 + wid] = ss; }
    __syncthreads();
    if (t == 0) {
        float S = 0.f, SS = 0.f;
        #pragma unroll
        for (int i = 0; i < 16; ++i) { S += red[i]; SS += red[16 + i]; }
        float m = S / (float)N;
        float var = SS / (float)N - m * m;
        sh_rs = rsqrtf(var + 1e-5f);
        sh_m = m;
    }
    __syncthreads();
    float rs = sh_rs, m = sh_m;
    short4v* out4 = (short4v*)(outb + base);
    for (int i = t; i < N / 4; i += 1024) {
        int ch = g * CPG_ + (i >> 10);
        float ga = gamma[ch] * rs;
        float be = beta[ch] - m * ga;
        float4 v = in4[i];
        short4v o;
        o.x = f2bf(fmaxf(fmaf(v.x, ga, be), 0.f));
        o.y = f2bf(fmaxf(fmaf(v.y, ga, be), 0.f));
        o.z = f2bf(fmaxf(fmaf(v.z, ga, be), 0.f));
        o.w = f2bf(fmaxf(fmaf(v.w, ga, be), 0.f));
        out4[i] = o;
    }
}

// bf16-input variant (reads layer-1 output y1 in bf16)
__global__ __launch_bounds__(1024) void gn_relu_bf16_kernel(
    const short* __restrict__ in, const float* __restrict__ gamma,
    const float* __restrict__ beta, short* __restrict__ outb)
{
    int b = blockIdx.x >> 5;
    int g = blockIdx.x & 31;
    const int N = CPG_ * HW_;
    size_t base = ((size_t)(b * C_ + g * CPG_)) * HW_;
    const short4v* in4 = (const short4v*)(in + base);
    int t = threadIdx.x;

    float s = 0.f, ss = 0.f;
    for (int i = t; i < N / 4; i += 1024) {
        short4v sv = in4[i];
        float vx = bf2f(sv.x), vy = bf2f(sv.y), vz = bf2f(sv.z), vw = bf2f(sv.w);
        s  += vx + vy + vz + vw;
        ss += vx * vx + vy * vy + vz * vz + vw * vw;
    }
    #pragma unroll
    for (int off = 32; off > 0; off >>= 1) {
        s  += __shfl_down(s, off, 64);
        ss += __shfl_down(ss, off, 64);
    }
    __shared__ float red[32];
    __shared__ float sh_rs, sh_m;
    int wid = t >> 6;
    if ((t & 63) == 0) { red[wid] = s; red[16 + wid] = ss; }
    __syncthreads();
    if (t == 0) {
        float S = 0.f, SS = 0.f;
        #pragma unroll
        for (int i = 0; i < 16; ++i) { S += red[i]; SS += red[16 + i]; }
        float m = S / (float)N;
        float var = SS / (float)N - m * m;
        sh_rs = rsqrtf(var + 1e-5f);
        sh_m = m;
    }
    __syncthreads();
    float rs = sh_rs, m = sh_m;
    short4v* out4 = (short4v*)(outb + base);
    for (int i = t; i < N / 4; i += 1024) {
        int ch = g * CPG_ + (i >> 10);
        float ga = gamma[ch] * rs;
        float be = beta[ch] - m * ga;
        short4v sv = in4[i];
        short4v o;
        o.x = f2bf(fmaxf(fmaf(bf2f(sv.x), ga, be), 0.f));
        o.y = f2bf(fmaxf(fmaf(bf2f(sv.y), ga, be), 0.f));
        o.z = f2bf(fmaxf(fmaf(bf2f(sv.z), ga, be), 0.f));
        o.w = f2bf(fmaxf(fmaf(bf2f(sv.w), ga, be), 0.f));
        out4[i] = o;
    }
}

// ---------------------------------------------------------------------------
// K2: depthwise 7x7 SAME conv, bf16 [C][HW] in -> bf16 [C][HW] out
// ---------------------------------------------------------------------------
__global__ __launch_bounds__(256) void dw7_kernel(
    const short* __restrict__ in, const float* __restrict__ dwk,
    short* __restrict__ out)
{
    int plane = blockIdx.x;
    int c = plane & (C_ - 1);
    const short* src = in + (size_t)plane * HW_;
    short* dst = out + (size_t)plane * HW_;
    __shared__ float tile[70 * 72];
    __shared__ float wk[49];
    int t = threadIdx.x;
    if (t < 49) wk[t] = dwk[c * 49 + t];
    for (int i = t; i < 70 * 72; i += 256) tile[i] = 0.f;
    __syncthreads();
    const short4v* src4 = (const short4v*)src;
    for (int i = t; i < HW_ / 4; i += 256) {
        short4v v = src4[i];
        int y = i >> 4, x = (i & 15) * 4;
        float* tp = &tile[(y + 3) * 72 + (x + 3)];
        tp[0] = bf2f(v.x); tp[1] = bf2f(v.y);
        tp[2] = bf2f(v.z); tp[3] = bf2f(v.w);
    }
    __syncthreads();
    #pragma unroll
    for (int it = 0; it < 4; ++it) {
        int idx = it * 256 + t;
        int y = idx >> 4;                 // 0..63
        int x0 = (idx & 15) * 4;          // 0..60
        float a0 = 0.f, a1 = 0.f, a2 = 0.f, a3 = 0.f;
        #pragma unroll
        for (int dy = 0; dy < 7; ++dy) {
            const float* tr = &tile[(y + dy) * 72 + x0];
            float4 ra = *(const float4*)tr;
            float4 rb = *(const float4*)(tr + 4);
            float4 rc = *(const float4*)(tr + 8);
            float r[12] = {ra.x, ra.y, ra.z, ra.w,
                           rb.x, rb.y, rb.z, rb.w,
                           rc.x, rc.y, rc.z, rc.w};
            const float* wr = &wk[dy * 7];
            #pragma unroll
            for (int dx = 0; dx < 7; ++dx) {
                float wv = wr[dx];
                a0 = fmaf(r[dx], wv, a0);
                a1 = fmaf(r[dx + 1], wv, a1);
                a2 = fmaf(r[dx + 2], wv, a2);
                a3 = fmaf(r[dx + 3], wv, a3);
            }
        }
        short4v o;
        o.x = f2bf(a0); o.y = f2bf(a1); o.z = f2bf(a2); o.w = f2bf(a3);
        *(short4v*)&dst[y * 64 + x0] = o;
    }
}

// ---------------------------------------------------------------------------
// K2b: LDS-tiled transpose bf16 [C][HW] -> [HW][C], both tensors in one
// launch (blk<256: A, else B). XCD-swizzled so the px-rows each XCD writes
// are the ones its deform blocks will gather (write-to-read L2 locality).
// ---------------------------------------------------------------------------
__global__ __launch_bounds__(256) void transpose2_kernel(
    const short* __restrict__ srcA, short* __restrict__ dstA,
    const short* __restrict__ srcB, short* __restrict__ dstB)
{
    int blk = blockIdx.x;                  // 0..511
    int h = blk >> 8;                      // 0: A, 1: B
    const short* src = h ? srcB : srcA;
    short*       dst = h ? dstB : dstA;
    int q0 = blk & 255;
    // XCD swizzle: XCD(bid)=bid%8 round-robin; give each XCD a contiguous
    // 32-logical-block chunk (matches deform_fused's swizzle).
    int q = ((q0 & 7) << 5) | (q0 >> 3);
    int b = q >> 6;
    int px0 = (q & 63) * 64;
    __shared__ unsigned ltile[64 * 132];   // 33 KB
    int t = threadIdx.x;
    const short* sb = src + (size_t)b * C_ * HW_;

    int pq4 = t & 15, cphi = t >> 4;
    #pragma unroll
    for (int i = 0; i < 8; ++i) {
        int cp = i * 16 + cphi;            // channel pair 0..127
        const short* r0 = sb + (size_t)(2 * cp) * HW_ + px0 + pq4 * 4;
        short4v lo = *(const short4v*)r0;
        short4v hi = *(const short4v*)(r0 + HW_);
        #pragma unroll
        for (int j = 0; j < 4; ++j) {
            int pl = pq4 * 4 + j;
            unsigned wrd = (unsigned)(unsigned short)lo[j]
                         | ((unsigned)(unsigned short)hi[j] << 16);
            ltile[pl * 132 + (cp ^ ((pl & 7) << 2))] = wrd;
        }
    }
    __syncthreads();

    int co = t & 31, ph = t >> 5;
    #pragma unroll
    for (int r = 0; r < 8; ++r) {
        int pl = r * 8 + ph;
        uint4 v = *(const uint4*)&ltile[pl * 132 + ((co * 4) ^ ((pl & 7) << 2))];
        *(uint4*)(dst + ((size_t)b * HW_ + px0 + pl) * C_ + co * 8) = v;
    }
}

// ---------------------------------------------------------------------------
// K3: pack weights. Blocks 0..4607: w1/w2 -> 32x32x16 A-fragment-major bf16.
// Fragment f = (g*16 + cc16)*8 + ot ; lane holds
// A[o = ot*32 + (lane&31)][c = cc16*16 + (lane>>5)*8 + j].
// Blocks 4608..4671: pw1/pw2 -> 16x16x32 A-frags padded to 32 rows.
// ---------------------------------------------------------------------------
__global__ __launch_bounds__(256) void wpack_all_kernel(
    const float* __restrict__ w1, const float* __restrict__ w2,
    const float* __restrict__ pw1, const float* __restrict__ pw2,
    short* __restrict__ wp1, short* __restrict__ wp2,
    short* __restrict__ ppk1, short* __restrict__ ppk2)
{
    int blk = blockIdx.x;
    if (blk < 4608) {
        const float* w = (blk < 2304) ? w1 : w2;
        short* wp = (blk < 2304) ? wp1 : wp2;
        int idx = (blk % 2304) * 256 + threadIdx.x;
        int j    = idx & 7;
        int lane = (idx >> 3) & 63;
        int ot   = (idx >> 9) & 7;                   // o-tile 0..7 (32 rows)
        int slab = idx >> 12;                        // 0..143 = g*16 + cc16
        int g = slab >> 4, cc16 = slab & 15;
        int o = ot * 32 + (lane & 31);
        int c = cc16 * 16 + (lane >> 5) * 8 + j;
        wp[idx] = f2bf(w[(size_t)(o * C_ + c) * KK_ + g]);
    } else {
        int q = blk - 4608;                          // 0..63
        const float* pw = (q < 32) ? pw1 : pw2;
        short* ppk = (q < 32) ? ppk1 : ppk2;
        int idx = (q & 31) * 256 + threadIdx.x;      // 0..8191
        int j = idx & 7, lane = (idx >> 3) & 63;
        int ot = (idx >> 9) & 1, sl = idx >> 10;     // 0..7
        int o = ot * 16 + (lane & 15);
        int k = sl * 32 + (lane >> 4) * 8 + j;
        ppk[idx] = (o < NOFF_) ? f2bf(pw[o * C_ + k]) : (short)0;
    }
}

// ---------------------------------------------------------------------------
// K4: fused deformable layer. One block (1024 thr = 16 waves) per (b,row),
// full C. XCD-aware block swizzle: each XCD owns 32 consecutive rows, so its
// ~1.2 MB gather window (rows r0-2..r0+33 x 256ch) + 1.2 MB weight pack stay
// resident in the 4 MB per-XCD L2 (was: round-robin rows -> every XCD
// streams the whole 8.4 MB tensor from HBM; FETCH_SIZE showed 4.4x).
// ---------------------------------------------------------------------------
__global__ __launch_bounds__(1024, 4) void deform_fused_kernel(
    const short* __restrict__ ht,   const short* __restrict__ fdw,
    const short* __restrict__ ppk,  const float* __restrict__ pwb,
    const short* __restrict__ wp,   const float* __restrict__ bias,
    const float* __restrict__ resid, float* __restrict__ outf,
    short* __restrict__ outb)
{
    // XCD swizzle (grid 256, 8 XCDs, round-robin bid%8): logical block
    // lb = (bid%8)*32 + bid/8 -> XCD x handles lb in [x*32, x*32+32).
    int lb = ((blockIdx.x & 7) << 5) | (blockIdx.x >> 3);
    int b = lb >> 6;
    int row = lb & 63;
    __shared__ int   i00[576], i01[576], i10[576], i11[576];
    __shared__ float c00[576], c01[576], c10[576], c11[576];
    __shared__ __align__(16) short sbuf[2][2][8192];  // [buf][panel][64px*128ch] = 64KB
    float* off_lds = (float*)&sbuf[0][0][0];          // 18*64 floats, dead before staging
    int t = threadIdx.x;
    int wv = t >> 6, lane = t & 63;
    int pq = lane >> 4, pr = lane & 15;
    int l31 = lane & 31, hi = lane >> 5;

    // ---- stage A: pw offsets via 16x16x32 MFMA (waves 0..7, full C) ----
    if (wv < 8) {
        int ot = wv & 1, ptw = wv >> 1;
        int px = ptw * 16 + pr;
        const short8* fb8 = (const short8*)(fdw +
            ((size_t)b * HW_ + row * 64 + px) * C_);
        const short8* ap = (const short8*)ppk;
        floatx4 pacc = (floatx4){0.f, 0.f, 0.f, 0.f};
        #pragma unroll
        for (int sl = 0; sl < 8; ++sl) {
            short8 af = ap[(sl * 2 + ot) * 64 + lane];
            short8 bf = fb8[sl * 4 + pq];
            pacc = __builtin_amdgcn_mfma_f32_16x16x32_bf16(af, bf, pacc, 0, 0, 0);
        }
        #pragma unroll
        for (int r = 0; r < 4; ++r) {
            int o = ot * 16 + pq * 4 + r;
            if (o < NOFF_) off_lds[o * 64 + px] = pacc[r] + pwb[o];
        }
    }
    __syncthreads();

    // ---- stage B: bilinear coefficient tables ----
    if (t < 576) {
        int e = t;
        int k = e >> 6, p = e & 63;
        float offy = off_lds[(2 * k) * 64 + p];
        float offx = off_lds[(2 * k + 1) * 64 + p];
        float py = (float)row + (float)(k / 3 - 1) + offy;
        float px = (float)p   + (float)(k % 3 - 1) + offx;
        float y0f = floorf(py), x0f = floorf(px);
        float wy1 = py - y0f, wx1 = px - x0f;
        float wy0 = 1.f - wy1, wx0 = 1.f - wx1;
        float y1f = y0f + 1.f, x1f = x0f + 1.f;
        bool vy0 = (y0f >= 0.f) && (y0f <= 63.f);
        bool vy1 = (y1f >= 0.f) && (y1f <= 63.f);
        bool vx0 = (x0f >= 0.f) && (x0f <= 63.f);
        bool vx1 = (x1f >= 0.f) && (x1f <= 63.f);
        int iy0 = (int)fminf(fmaxf(y0f, 0.f), 63.f);
        int iy1 = (int)fminf(fmaxf(y1f, 0.f), 63.f);
        int ix0 = (int)fminf(fmaxf(x0f, 0.f), 63.f);
        int ix1 = (int)fminf(fmaxf(x1f, 0.f), 63.f);
        i00[e] = iy0 * 64 + ix0; i01[e] = iy0 * 64 + ix1;
        i10[e] = iy1 * 64 + ix0; i11[e] = iy1 * 64 + ix1;
        c00[e] = (vy0 && vx0) ? wy0 * wx0 : 0.f;
        c01[e] = (vy0 && vx1) ? wy0 * wx1 : 0.f;
        c10[e] = (vy1 && vx0) ? wy1 * wx0 : 0.f;
        c11[e] = (vy1 && vx1) ? wy1 * wx1 : 0.f;
    }
    __syncthreads();

    // ---- stage C: 9 taps, full C, double-buffered ----
    // thread map: c8a = t&7 (octet), pan = (t>>3)&1 (128-ch panel), spx = t>>4.
    int c8a = t & 7;
    int pan = (t >> 3) & 1;
    int spx = t >> 4;                       // 0..63
    const short* hb = ht + ((size_t)b * HW_) * C_ + pan * 128 + c8a * 8;
    const short* hb0 = hb;                  // octet c8a of panel
    const short* hb1 = hb + 64;             // octet c8a+8 of panel
    // per-panel LDS slot swizzle: slot = oct ^ (px & 15); conflict-free.
    int slotA = (c8a ^ (spx & 15)) * 8;
    int slotB = ((c8a + 8) ^ (spx & 15)) * 8;
    int srow = spx * 128;

    short8 ra[4], rb[4];
    auto prefetch = [&](int g) {
        int e = g * 64 + spx;
        int a00 = i00[e], a01 = i01[e], a10 = i10[e], a11 = i11[e];
        ra[0] = *(const short8*)(hb0 + (size_t)a00 * C_);
        ra[1] = *(const short8*)(hb0 + (size_t)a01 * C_);
        ra[2] = *(const short8*)(hb0 + (size_t)a10 * C_);
        ra[3] = *(const short8*)(hb0 + (size_t)a11 * C_);
        rb[0] = *(const short8*)(hb1 + (size_t)a00 * C_);
        rb[1] = *(const short8*)(hb1 + (size_t)a01 * C_);
        rb[2] = *(const short8*)(hb1 + (size_t)a10 * C_);
        rb[3] = *(const short8*)(hb1 + (size_t)a11 * C_);
    };
    auto stage_write = [&](int g, int bi) {
        int e = g * 64 + spx;
        float w00 = c00[e], w01 = c01[e], w10 = c10[e], w11 = c11[e];
        uint4 va, vb;
        float f0, f1;
        #define BLEND(R, J) (w00 * bf2f(R[0][J]) + w01 * bf2f(R[1][J]) \
                           + w10 * bf2f(R[2][J]) + w11 * bf2f(R[3][J]))
        f0 = BLEND(ra, 0); f1 = BLEND(ra, 1); va.x = pkbf(f0, f1);
        f0 = BLEND(ra, 2); f1 = BLEND(ra, 3); va.y = pkbf(f0, f1);
        f0 = BLEND(ra, 4); f1 = BLEND(ra, 5); va.z = pkbf(f0, f1);
        f0 = BLEND(ra, 6); f1 = BLEND(ra, 7); va.w = pkbf(f0, f1);
        f0 = BLEND(rb, 0); f1 = BLEND(rb, 1); vb.x = pkbf(f0, f1);
        f0 = BLEND(rb, 2); f1 = BLEND(rb, 3); vb.y = pkbf(f0, f1);
        f0 = BLEND(rb, 4); f1 = BLEND(rb, 5); vb.z = pkbf(f0, f1);
        f0 = BLEND(rb, 6); f1 = BLEND(rb, 7); vb.w = pkbf(f0, f1);
        #undef BLEND
        short* sp = &sbuf[bi][pan][srow];
        *(uint4*)&sp[slotA] = va;
        *(uint4*)&sp[slotB] = vb;
    };

    // wave role: pairId = o-tile (32 rows), half = K-half (128 channels)
    int pairId = wv & 7;
    int half = wv >> 3;

    floatx16 acc[2];
    #pragma unroll
    for (int i = 0; i < 16; ++i) { acc[0][i] = 0.f; acc[1][i] = 0.f; }

    prefetch(0);
    stage_write(0, 0);
    prefetch(1);
    __syncthreads();

    const short8* wp8 = (const short8*)wp;
    int msk = l31 & 15;

    for (int g = 0; g < 9; ++g) {
        const short* sb = &sbuf[g & 1][half][0];
        #pragma unroll
        for (int q4 = 0; q4 < 2; ++q4) {
            short8 af[4];
            #pragma unroll
            for (int qq = 0; qq < 4; ++qq)
                af[qq] = wp8[(size_t)(((g * 16 + half * 8 + q4 * 4 + qq) * 8 + pairId) * 64 + lane)];
            #pragma unroll
            for (int qq = 0; qq < 4; ++qq) {
                int ksl = q4 * 4 + qq;                       // local slab 0..7
                int so = ((((ksl << 1) | hi) ^ msk) << 3);
                short8 b0 = *(const short8*)&sb[l31 * 128 + so];
                short8 b1 = *(const short8*)&sb[(32 + l31) * 128 + so];
                acc[0] = __builtin_amdgcn_mfma_f32_32x32x16_bf16(af[qq], b0, acc[0], 0, 0, 0);
                acc[1] = __builtin_amdgcn_mfma_f32_32x32x16_bf16(af[qq], b1, acc[1], 0, 0, 0);
            }
        }
        if (g + 1 < 9) {
            stage_write(g + 1, (g + 1) & 1);
            if (g + 2 < 9) prefetch(g + 2);
        }
        __syncthreads();
    }

    // ---- combine K-halves in LDS (lane-major planes, conflict-free) ----
    // wave wv (half=0) writes its pxt=1 partial; wv+8 (half=1) writes pxt=0.
    float* xch = (float*)&sbuf[0][0][0];     // 16 regions x 4KB = 64KB
    int wreg = (pairId * 2 + half) * 1024;   // floats
    floatx16 aw = half ? acc[0] : acc[1];
    floatx4* xq = (floatx4*)xch;
    #pragma unroll
    for (int j = 0; j < 4; ++j) {
        floatx4 v = {aw[j * 4 + 0], aw[j * 4 + 1], aw[j * 4 + 2], aw[j * 4 + 3]};
        xq[(wreg >> 2) + j * 64 + lane] = v;
    }
    __syncthreads();
    int rreg = (pairId * 2 + (half ^ 1)) * 1024;
    floatx16 ac = half ? acc[1] : acc[0];
    #pragma unroll
    for (int j = 0; j < 4; ++j) {
        floatx4 v = xq[(rreg >> 2) + j * 64 + lane];
        ac[j * 4 + 0] += v.x; ac[j * 4 + 1] += v.y;
        ac[j * 4 + 2] += v.z; ac[j * 4 + 3] += v.w;
    }

    // ---- epilogue: wave stores its px-tile (pxt = half) ----
    // C/D 32x32: col = lane&31 (px), row = (r&3) + 8*(r>>2) + 4*hi (o)
    #pragma unroll
    for (int r = 0; r < 16; ++r) {
        int o = pairId * 32 + (r & 3) + 8 * (r >> 2) + 4 * hi;
        float v = ac[r] + bias[o];
        size_t ob = ((size_t)(b * C_ + o)) * HW_ + row * 64 + half * 32 + l31;
        if (outf) {
            if (resid) v += resid[ob];
            outf[ob] = v;
        } else {
            outb[ob] = f2bf(v);
        }
    }
}

// ---------------------------------------------------------------------------
extern "C" void kernel_launch(void* const* d_in, const int* in_sizes, int n_in,
                              void* d_out, int out_size, void* d_ws, size_t ws_size,
                              hipStream_t stream)
{
    const float* x     = (const float*)d_in[0];
    const float* gn1_g = (const float*)d_in[1];
    const float* gn1_b = (const float*)d_in[2];
    const float* dw1   = (const float*)d_in[3];
    const float* pw1   = (const float*)d_in[4];
    const float* pwb1  = (const float*)d_in[5];
    const float* w1    = (const float*)d_in[6];
    const float* b1    = (const float*)d_in[7];
    const float* gn2_g = (const float*)d_in[8];
    const float* gn2_b = (const float*)d_in[9];
    const float* dw2   = (const float*)d_in[10];
    const float* pw2   = (const float*)d_in[11];
    const float* pwb2  = (const float*)d_in[12];
    const float* w2    = (const float*)d_in[13];
    const float* b2    = (const float*)d_in[14];
    float* out = (float*)d_out;

    float* ws   = (float*)d_ws;
    short* y1b  = (short*)ws;                  // bf16 [B][C][HW]  (8 MB)
    short* hbf  = (short*)(ws + 2097152);      // bf16 [B][C][HW]  (8 MB)
    short* hbt  = (short*)(ws + 4194304);      // bf16 [B][HW][C]  (8 MB)
    short* fdwc = (short*)(ws + 6291456);      // bf16 [B][C][HW]  (8 MB)
    short* fdwt = (short*)(ws + 8388608);      // bf16 [B][HW][C]  (8 MB)
    short* wp1  = (short*)(ws + 10485760);     // 589,824 bf16
    short* wp2  = (short*)(ws + 10780672);     // 589,824 bf16
    short* ppk1 = (short*)(ws + 11075584);     // 8,192 bf16
    short* ppk2 = (short*)(ws + 11079680);     // 8,192 bf16

    wpack_all_kernel<<<4672, 256, 0, stream>>>(w1, w2, pw1, pw2,
                                               wp1, wp2, ppk1, ppk2);

    // layer 1
    gn_relu_f32_kernel<<<B_ * NG_, 1024, 0, stream>>>(x, gn1_g, gn1_b, hbf);
    dw7_kernel<<<B_ * C_, 256, 0, stream>>>(hbf, dw1, fdwc);
    transpose2_kernel<<<512, 256, 0, stream>>>(hbf, hbt, fdwc, fdwt);
    deform_fused_kernel<<<B_ * H_, 1024, 0, stream>>>(
        hbt, fdwt, ppk1, pwb1, wp1, b1, nullptr, nullptr, y1b);

    // layer 2 (+ residual x)
    gn_relu_bf16_kernel<<<B_ * NG_, 1024, 0, stream>>>(y1b, gn2_g, gn2_b, hbf);
    dw7_kernel<<<B_ * C_, 256, 0, stream>>>(hbf, dw2, fdwc);
    transpose2_kernel<<<512, 256, 0, stream>>>(hbf, hbt, fdwc, fdwt);
    deform_fused_kernel<<<B_ * H_, 1024, 0, stream>>>(
        hbt, fdwt, ppk2, pwb2, wp2, b2, x, out, nullptr);
}